// Round 3
// baseline (713.934 us; speedup 1.0000x reference)
//
#include <hip/hip_runtime.h>
#include <hip/hip_bf16.h>

#define D 128
#define DH 64  // D/2 (pairs)

typedef unsigned int uint32;

__device__ __forceinline__ float bflo(uint32 u) { return __uint_as_float(u << 16); }
__device__ __forceinline__ float bfhi(uint32 u) { return __uint_as_float(u & 0xffff0000u); }

// dual-dtype loads from the raw x buffer (flag: 1 = bf16, 0 = fp32)
__device__ __forceinline__ float load_x1(const void* x, long idx, int flag) {
    if (flag) return __bfloat162float(((const __hip_bfloat16*)x)[idx]);
    return ((const float*)x)[idx];
}
__device__ __forceinline__ float2 load_x2(const void* x, long pidx, int flag) {
    if (flag) { uint32 u = ((const uint32*)x)[pidx]; return make_float2(bflo(u), bfhi(u)); }
    return ((const float2*)x)[pidx];
}

// ---------------------------------------------------------------------------
// Kernel 0: detect dtype of float tensors; canonicalize W/b/gamma/beta/eps to
// fp32 in ws. par[0..127]=b, [128..255]=gamma, [256..383]=beta, [384]=1+eps,
// int slot [385]=flag.
// ---------------------------------------------------------------------------
__global__ __launch_bounds__(256) void detect_prep_kernel(
    const void* __restrict__ xr, const void* __restrict__ Wr,
    const void* __restrict__ br, const void* __restrict__ gr,
    const void* __restrict__ ber, const void* __restrict__ er,
    float* __restrict__ par, float* __restrict__ Wf)
{
    __shared__ int cnt_s;
    if (threadIdx.x == 0) cnt_s = 0;
    __syncthreads();
    // probe: low 16 bits of each word decode to a plausible bf16 iff x is bf16
    const uint32* xw = (const uint32*)xr;
    int hits = 0;
    for (int k = threadIdx.x; k < 2048; k += 256) {
        uint32 e = (xw[k] >> 7) & 0xFFu;   // exponent field of low-half bf16
        hits += (e >= 122u && e <= 132u) ? 1 : 0;
    }
    atomicAdd(&cnt_s, hits);
    __syncthreads();
    const int flag = (cnt_s >= 1024) ? 1 : 0;

    if (threadIdx.x < D) {
        int k = threadIdx.x;
        if (flag) {
            par[k]       = __bfloat162float(((const __hip_bfloat16*)br)[k]);
            par[128 + k] = __bfloat162float(((const __hip_bfloat16*)gr)[k]);
            par[256 + k] = __bfloat162float(((const __hip_bfloat16*)ber)[k]);
        } else {
            par[k]       = ((const float*)br)[k];
            par[128 + k] = ((const float*)gr)[k];
            par[256 + k] = ((const float*)ber)[k];
        }
    }
    if (threadIdx.x == 0) {
        float e = flag ? __bfloat162float(((const __hip_bfloat16*)er)[0])
                       : ((const float*)er)[0];
        par[384] = 1.0f + e;
        ((int*)par)[385] = flag;
    }
    // canonicalize W (D*D elements = 8192 pairs)
    for (int k = threadIdx.x; k < (D * D) / 2; k += 256) {
        float2 v;
        if (flag) { uint32 u = ((const uint32*)Wr)[k]; v = make_float2(bflo(u), bfhi(u)); }
        else      { v = ((const float2*)Wr)[k]; }
        ((float2*)Wf)[k] = v;
    }
}

// ---------------------------------------------------------------------------
// Kernel 1: edge scatter  agg[dst,:] += x[src,:]   (fp32 atomics)
// one thread per (edge, feature-pair): 2 atomics / thread
// ---------------------------------------------------------------------------
__global__ __launch_bounds__(256) void scatter_kernel(
    const void* __restrict__ xr, const int* __restrict__ src,
    const int* __restrict__ dst, const float* __restrict__ par,
    float* __restrict__ agg, long total)
{
    const int flag = ((const int*)par)[385];
    long t = (long)blockIdx.x * 256 + threadIdx.x;
    if (t >= total) return;
    int e = (int)(t >> 6);
    int f = (int)(t & 63);
    int s = src[e];
    int d = dst[e];
    float2 v = load_x2(xr, (long)s * DH + f, flag);
    unsafeAtomicAdd(&agg[(long)d * D + 2 * f],     v.x);
    unsafeAtomicAdd(&agg[(long)d * D + 2 * f + 1], v.y);
}

// ---------------------------------------------------------------------------
// Kernel 2: h = (1+eps)*x + agg ; hlin = h @ W^T + b (bf16 out, fp32 math) ;
//           accumulate column sum / sumsq for BN.
// block = 256; threads 0-127 -> row r col j, 128-255 -> row r+1 col j.
// W row j in 128 VGPRs; h row broadcast from LDS (b128 reads).
// hlin may alias d_out (bf16 staging; same-index overwrite later is safe).
// ---------------------------------------------------------------------------
__global__ __launch_bounds__(256) void gemm_stats_kernel(
    const void* __restrict__ xr, const float* __restrict__ agg,
    const float* __restrict__ Wf, const float* __restrict__ par,
    __hip_bfloat16* __restrict__ hlin, float* __restrict__ stats, int N)
{
    __shared__ __align__(16) float hrow[2][D];
    __shared__ float red[256];

    const int tid  = threadIdx.x;
    const int j    = tid & (D - 1);
    const int half = tid >> 7;
    const int flag = ((const int*)par)[385];

    float w[D];
    {
        const float4* Wq = (const float4*)(Wf + j * D);
        #pragma unroll
        for (int q = 0; q < 32; ++q) {
            float4 u = Wq[q];
            w[4*q+0] = u.x; w[4*q+1] = u.y; w[4*q+2] = u.z; w[4*q+3] = u.w;
        }
    }
    const float eps1 = par[384];
    const float bj   = par[j];

    float psum = 0.0f, psq = 0.0f;
    const int row0 = blockIdx.x * 128;

    for (int it = 0; it < 64; ++it) {
        const int i = row0 + it * 2 + half;
        const bool valid = (i < N);
        if (valid) {
            long o = (long)i * D + j;
            hrow[half][j] = fmaf(eps1, load_x1(xr, o, flag), agg[o]);
        }
        __syncthreads();
        if (valid) {
            const float4* hp = (const float4*)hrow[half];
            float a0 = 0.f, a1 = 0.f, a2 = 0.f, a3 = 0.f;
            #pragma unroll
            for (int q = 0; q < 8; ++q) {
                float4 hA = hp[4*q+0], hB = hp[4*q+1], hC = hp[4*q+2], hD = hp[4*q+3];
                a0 = fmaf(hA.x, w[16*q+ 0], a0); a0 = fmaf(hA.y, w[16*q+ 1], a0);
                a0 = fmaf(hA.z, w[16*q+ 2], a0); a0 = fmaf(hA.w, w[16*q+ 3], a0);
                a1 = fmaf(hB.x, w[16*q+ 4], a1); a1 = fmaf(hB.y, w[16*q+ 5], a1);
                a1 = fmaf(hB.z, w[16*q+ 6], a1); a1 = fmaf(hB.w, w[16*q+ 7], a1);
                a2 = fmaf(hC.x, w[16*q+ 8], a2); a2 = fmaf(hC.y, w[16*q+ 9], a2);
                a2 = fmaf(hC.z, w[16*q+10], a2); a2 = fmaf(hC.w, w[16*q+11], a2);
                a3 = fmaf(hD.x, w[16*q+12], a3); a3 = fmaf(hD.y, w[16*q+13], a3);
                a3 = fmaf(hD.z, w[16*q+14], a3); a3 = fmaf(hD.w, w[16*q+15], a3);
            }
            float acc = bj + ((a0 + a1) + (a2 + a3));
            hlin[(long)i * D + j] = __float2bfloat16(acc);
            psum += acc;
            psq  = fmaf(acc, acc, psq);
        }
        __syncthreads();
    }

    red[tid] = psum;
    __syncthreads();
    float s2 = (tid < 128) ? (red[tid] + red[tid + 128]) : 0.0f;
    __syncthreads();
    red[tid] = psq;
    __syncthreads();
    if (tid < 128) {
        unsafeAtomicAdd(&stats[j],       s2);
        unsafeAtomicAdd(&stats[128 + j], red[tid] + red[tid + 128]);
    }
}

// ---------------------------------------------------------------------------
// Kernel 3: finalize BN -> ginv = gamma*rsqrt(var+eps), shift = beta-mean*ginv
// stats: [0..127]=sum [128..255]=sumsq [256..383]=ginv [384..511]=shift
// ---------------------------------------------------------------------------
__global__ void finalize_kernel(const float* __restrict__ par,
                                float* __restrict__ stats, float invN)
{
    int j = threadIdx.x;  // 0..127
    float mean = stats[j] * invN;
    float var  = stats[128 + j] * invN - mean * mean;
    float ginv = par[128 + j] * rsqrtf(var + 1e-5f);
    stats[256 + j] = ginv;
    stats[384 + j] = par[256 + j] - mean * ginv;
}

// ---------------------------------------------------------------------------
// Kernel 4: out = relu(hlin*ginv + shift) + x   (pair-granular, dual out)
// hlin2 may alias dout: thread t reads word t then writes word t (bf16 mode).
// ---------------------------------------------------------------------------
__global__ __launch_bounds__(256) void out_kernel(
    const uint32* __restrict__ hlin2, const void* __restrict__ xr,
    const float* __restrict__ par, const float* __restrict__ stats,
    void* __restrict__ dout, long total)
{
    __shared__ float ginv[D], sh[D];
    if (threadIdx.x < D) {
        ginv[threadIdx.x] = stats[256 + threadIdx.x];
        sh[threadIdx.x]   = stats[384 + threadIdx.x];
    }
    __syncthreads();
    const int flag = ((const int*)par)[385];
    long t = (long)blockIdx.x * 256 + threadIdx.x;
    if (t >= total) return;
    int f = (int)(t & 63);
    uint32 hu = hlin2[t];
    float2 xv = load_x2(xr, t, flag);
    float v0 = fmaf(bflo(hu), ginv[2 * f],     sh[2 * f]);
    float v1 = fmaf(bfhi(hu), ginv[2 * f + 1], sh[2 * f + 1]);
    v0 = fmaxf(v0, 0.0f) + xv.x;
    v1 = fmaxf(v1, 0.0f) + xv.y;
    if (flag) {
        ((__hip_bfloat162*)dout)[t] =
            __halves2bfloat162(__float2bfloat16(v0), __float2bfloat16(v1));
    } else {
        ((float2*)dout)[t] = make_float2(v0, v1);
    }
}

// ---------------------------------------------------------------------------
extern "C" void kernel_launch(void* const* d_in, const int* in_sizes, int n_in,
                              void* d_out, int out_size, void* d_ws, size_t ws_size,
                              hipStream_t stream)
{
    const void* x     = d_in[0];
    const int*  ei    = (const int*)d_in[1];
    const void* W     = d_in[2];
    const void* b     = d_in[3];
    const void* gamma = d_in[4];
    const void* beta  = d_in[5];
    const void* geps  = d_in[6];

    const int N = in_sizes[0] / D;
    const int E = in_sizes[1] / 2;
    const int* src = ei;        // edge_index[0,:]
    const int* dst = ei + E;    // edge_index[1,:]

    // ws layout: [agg fp32 N*D][stats 512f][par 512f][Wf fp32 D*D] (~20.6 MB)
    // hlin (bf16 N*D) stages in d_out unless ws has room for it.
    char* ws = (char*)d_ws;
    float* agg   = (float*)ws;
    float* stats = (float*)(ws + (size_t)N * D * 4);
    float* par   = (float*)(ws + (size_t)N * D * 4 + 2048);
    float* Wf    = (float*)(ws + (size_t)N * D * 4 + 4096);
    size_t base  = (size_t)N * D * 4 + 4096 + (size_t)D * D * 4;

    __hip_bfloat16* hlin;
    if (ws_size >= base + (size_t)N * D * 2)
        hlin = (__hip_bfloat16*)(ws + base);   // ws roomy: keep staging in ws
    else
        hlin = (__hip_bfloat16*)d_out;         // stage in d_out (same-index alias, safe)

    // zero agg + stats[0..255] (sum/sumsq); ws is re-poisoned 0xAA each call
    hipMemsetAsync(agg, 0, (size_t)N * D * 4 + 1024, stream);

    detect_prep_kernel<<<1, 256, 0, stream>>>(x, W, b, gamma, beta, geps, par, Wf);

    long stot = (long)E * 64;
    scatter_kernel<<<(int)((stot + 255) / 256), 256, 0, stream>>>(
        x, src, dst, par, agg, stot);

    int gb = (N + 127) / 128;
    gemm_stats_kernel<<<gb, 256, 0, stream>>>(x, agg, Wf, par, hlin, stats, N);

    finalize_kernel<<<1, 128, 0, stream>>>(par, stats, 1.0f / (float)N);

    long ototal = (long)N * DH;
    out_kernel<<<(int)((ototal + 255) / 256), 256, 0, stream>>>(
        (const uint32*)hlin, x, par, stats, (void*)d_out, ototal);
}